// Round 1
// baseline (101.062 us; speedup 1.0000x reference)
//
#include <hip/hip_runtime.h>
#include <math.h>

// HybridQLSTM: the reference broadcasts a scalar expectation across the tag
// axis and then log_softmax's it. log_softmax of a constant-length-T vector is
// -ln(T) for every entry, independent of the LSTM/embedding computation.
// Output = fill(-log(tagset_size)) over S*B*T elements.

__global__ __launch_bounds__(256) void HybridQLSTM_fill_kernel(
    const int* __restrict__ tagset_size,
    float* __restrict__ out,
    int n) {
    // Wave-uniform scalar load; compiler emits s_load + readfirstlane-style
    // uniform path. -logf of a small positive int is exact to ~1 ulp.
    float v = -logf((float)tagset_size[0]);

    int i = blockIdx.x * blockDim.x + threadIdx.x;
    int base = i * 4;
    if (base + 3 < n) {
        // Coalesced 16 B/lane vector store.
        float4* o = (float4*)(out + base);
        *o = make_float4(v, v, v, v);
    } else {
        // Tail (not hit for n = 819200, kept for robustness).
        for (int j = base; j < n; ++j) out[j] = v;
    }
}

extern "C" void kernel_launch(void* const* d_in, const int* in_sizes, int n_in,
                              void* d_out, int out_size, void* d_ws, size_t ws_size,
                              hipStream_t stream) {
    // Inputs (setup_inputs order):
    //   d_in[0] sentence  [SEQ, BATCH] int32   (unused — dead code w.r.t. output)
    //   d_in[1] tagset_size (scalar int)       (the only live input)
    //   d_in[2] emb, d_in[3] W_ih, d_in[4] W_hh, d_in[5] b_ih, d_in[6] b_hh (unused)
    const int* tagset = (const int*)d_in[1];
    float* out = (float*)d_out;

    int n = out_size;                       // 512*32*50 = 819200
    int threads = 256;
    int vecs = (n + 3) / 4;                 // float4 stores
    int blocks = (vecs + threads - 1) / threads;

    HybridQLSTM_fill_kernel<<<blocks, threads, 0, stream>>>(tagset, out, n);
}